// Round 1
// baseline (456.872 us; speedup 1.0000x reference)
//
#include <hip/hip_runtime.h>
#include <hip/hip_bf16.h>
#include <math.h>

#define S_LEN 2048
#define BATCH 2
#define NH 16
#define DK 64
#define DM 1024
#define BS (BATCH * S_LEN)      /* 4096 rows */
#define BHS (BATCH * NH * S_LEN) /* 65536 head-rows */

using bf16x8  = __attribute__((ext_vector_type(8))) __bf16;
using floatx4 = __attribute__((ext_vector_type(4))) float;
using ushort8v = __attribute__((ext_vector_type(8))) unsigned short;
using ushort4v = __attribute__((ext_vector_type(4))) unsigned short;
using floatx4v = floatx4;

__device__ __forceinline__ unsigned short f2bf(float f) {
    union { float f; unsigned u; } v; v.f = f;
    unsigned r = v.u + 0x7fffu + ((v.u >> 16) & 1u);
    return (unsigned short)(r >> 16);
}

// async global->LDS, 16 bytes per lane. LDS dest must be wave-uniform base + lane*16.
__device__ __forceinline__ void gl2lds16(const void* g, void* l) {
    __builtin_amdgcn_global_load_lds(
        (__attribute__((address_space(1))) void*)(uintptr_t)g,
        (__attribute__((address_space(3))) void*)(uintptr_t)l,
        16, 0, 0);
}

// ---------------- prep: fp32 -> bf16 convert for Q,K,V ----------------
__global__ void k_convert(const float* __restrict__ q, const float* __restrict__ k,
                          const float* __restrict__ v,
                          unsigned short* __restrict__ qb, unsigned short* __restrict__ kb,
                          unsigned short* __restrict__ vb) {
    const int N4 = BS * DM / 4;
    int i = blockIdx.x * 256 + threadIdx.x;   // 0 .. 3*N4-1
    int which = i / N4;
    int off = i - which * N4;
    const floatx4* src = (const floatx4*)(which == 0 ? q : which == 1 ? k : v);
    unsigned short* dst = which == 0 ? qb : which == 1 ? kb : vb;
    floatx4 x = src[off];
    ushort4v o;
    o[0] = f2bf(x[0]); o[1] = f2bf(x[1]); o[2] = f2bf(x[2]); o[3] = f2bf(x[3]);
    ((ushort4v*)dst)[off] = o;
}

// ---------------- prep: transpose square fp32 matrix -> bf16 [N][K] ----------------
__global__ void k_transpose(const float* s0, const float* s1, const float* s2, const float* s3,
                            unsigned short* d0, unsigned short* d1, unsigned short* d2,
                            unsigned short* d3, int n) {
    int z = blockIdx.z;
    const float* src = z == 0 ? s0 : z == 1 ? s1 : z == 2 ? s2 : s3;
    unsigned short* dst = z == 0 ? d0 : z == 1 ? d1 : z == 2 ? d2 : d3;
    __shared__ unsigned short tile[32][33];
    int tx = threadIdx.x & 31, ty = threadIdx.x >> 5;  // ty 0..7
#pragma unroll
    for (int i = 0; i < 4; i++) {
        int y = blockIdx.y * 32 + i * 8 + ty;
        tile[i * 8 + ty][tx] = f2bf(src[(size_t)y * n + blockIdx.x * 32 + tx]);
    }
    __syncthreads();
#pragma unroll
    for (int i = 0; i < 4; i++) {
        int r = blockIdx.x * 32 + i * 8 + ty;
        dst[(size_t)r * n + blockIdx.y * 32 + tx] = tile[tx][i * 8 + ty];
    }
}

// ---------------- prep: pack mask int32 -> bitmask ----------------
__global__ void k_maskpack(const int* __restrict__ mask, unsigned int* __restrict__ mb) {
    int t = blockIdx.x * 256 + threadIdx.x;     // 0 .. 2048*64-1
    int row = t >> 6, w = t & 63;
    const int* p = mask + (size_t)row * S_LEN + w * 32;
    unsigned bits = 0;
#pragma unroll
    for (int i = 0; i < 32; i++) bits |= (p[i] != 0 ? 1u : 0u) << i;
    mb[t] = bits;
}

// ---------------- 128x128 bf16 GEMM: C = A[M,K] @ Wt[N,K]^T + bias ----------------
// mode 0: store bf16 head-split [B][H][S][DK];  mode 1: store fp32 row-major [M][N]
__global__ __launch_bounds__(256) void k_gemm128(const unsigned short* __restrict__ A,
                                                 const unsigned short* __restrict__ Wt,
                                                 const float* __restrict__ bias,
                                                 unsigned short* __restrict__ out_hs,
                                                 float* __restrict__ out_f32, int mode) {
    const int K = DM;
    int m0 = blockIdx.y * 128, n0 = blockIdx.x * 128;
    __shared__ unsigned short As[128 * 32];
    __shared__ unsigned short Bs[128 * 32];
    int tid = threadIdx.x;
    int lane = tid & 63, wid = tid >> 6;
    int wy = wid >> 1, wx = wid & 1;
    int l16 = lane & 15, quad = lane >> 4;

    floatx4 acc[4][4] = {};

    for (int kt = 0; kt < K / 32; kt++) {
        int kk = kt * 32;
#pragma unroll
        for (int i = 0; i < 2; i++) {
            int c = i * 256 + tid;
            int row = c >> 2, seg = c & 3;
            gl2lds16(A + (size_t)(m0 + row) * K + kk + seg * 8, &As[c * 8]);
            gl2lds16(Wt + (size_t)(n0 + row) * K + kk + seg * 8, &Bs[c * 8]);
        }
        __syncthreads();
        bf16x8 af[4], bf[4];
#pragma unroll
        for (int mi = 0; mi < 4; mi++)
            af[mi] = *(const bf16x8*)&As[(wy * 64 + mi * 16 + l16) * 32 + quad * 8];
#pragma unroll
        for (int ni = 0; ni < 4; ni++)
            bf[ni] = *(const bf16x8*)&Bs[(wx * 64 + ni * 16 + l16) * 32 + quad * 8];
#pragma unroll
        for (int mi = 0; mi < 4; mi++)
#pragma unroll
            for (int ni = 0; ni < 4; ni++)
                acc[mi][ni] = __builtin_amdgcn_mfma_f32_16x16x32_bf16(af[mi], bf[ni], acc[mi][ni], 0, 0, 0);
        __syncthreads();
    }

#pragma unroll
    for (int mi = 0; mi < 4; mi++) {
#pragma unroll
        for (int ni = 0; ni < 4; ni++) {
            int col = n0 + wx * 64 + ni * 16 + l16;
            float bv = bias[col];
#pragma unroll
            for (int r = 0; r < 4; r++) {
                int row = m0 + wy * 64 + mi * 16 + quad * 4 + r;
                float val = acc[mi][ni][r] + bv;
                if (mode == 0) {
                    int b = row >> 11, s = row & (S_LEN - 1);
                    out_hs[(size_t)((b * NH + (col >> 6)) * S_LEN + s) * DK + (col & 63)] = f2bf(val);
                } else {
                    out_f32[(size_t)row * DM + col] = val;
                }
            }
        }
    }
}

// ---------------- feature map: dst = tanh(src[M,64] @ wt[64,64]^T + bias) ----------------
__global__ __launch_bounds__(256) void k_feature(const unsigned short* __restrict__ src,
                                                 const unsigned short* __restrict__ wt,
                                                 const float* __restrict__ bias,
                                                 unsigned short* __restrict__ dst) {
    int tid = threadIdx.x, lane = tid & 63, wid = tid >> 6;
    int l16 = lane & 15, quad = lane >> 4;
    int r0 = blockIdx.x * 64 + wid * 16;

    bf16x8 af[2];
#pragma unroll
    for (int ks = 0; ks < 2; ks++)
        af[ks] = *(const bf16x8*)(src + (size_t)(r0 + l16) * DK + ks * 32 + quad * 8);

    floatx4 acc[4] = {};
#pragma unroll
    for (int ni = 0; ni < 4; ni++) {
#pragma unroll
        for (int ks = 0; ks < 2; ks++) {
            bf16x8 bf = *(const bf16x8*)(wt + (size_t)(ni * 16 + l16) * DK + ks * 32 + quad * 8);
            acc[ni] = __builtin_amdgcn_mfma_f32_16x16x32_bf16(af[ks], bf, acc[ni], 0, 0, 0);
        }
    }
#pragma unroll
    for (int ni = 0; ni < 4; ni++) {
        int col = ni * 16 + l16;
        float bv = bias[col];
#pragma unroll
        for (int r = 0; r < 4; r++) {
            float t = tanhf(acc[ni][r] + bv);
            dst[(size_t)(r0 + quad * 4 + r) * DK + col] = f2bf(t);
        }
    }
}

// ---------------- flash attention ----------------
// grid: (S/64 q-tiles, B*H). block 256 = 4 waves, each wave owns 16 q rows.
__global__ __launch_bounds__(256) void k_attn(const unsigned short* __restrict__ qf,
                                              const unsigned short* __restrict__ kf,
                                              const unsigned short* __restrict__ vh,
                                              const unsigned int* __restrict__ mb,
                                              const float* __restrict__ temp,
                                              unsigned short* __restrict__ ctx) {
    int tid = threadIdx.x, lane = tid & 63, wid = tid >> 6;
    int l16 = lane & 15, quad = lane >> 4;
    int bh = blockIdx.y;
    int b = bh >> 4, h = bh & 15;
    int q0 = blockIdx.x * 64 + wid * 16;

    const unsigned short* qfb = qf + (size_t)bh * S_LEN * DK;
    const unsigned short* kfb = kf + (size_t)bh * S_LEN * DK;
    const unsigned short* vb = vh + (size_t)bh * S_LEN * DK;
    float scale = 1.0f / (8.0f * temp[h]);

    __shared__ unsigned short Plds[4][16 * 64];
    __shared__ unsigned short Vt[64 * 64];   // [d][key]

    bf16x8 aq[2];
#pragma unroll
    for (int ks = 0; ks < 2; ks++)
        aq[ks] = *(const bf16x8*)(qfb + (size_t)(q0 + l16) * DK + ks * 32 + quad * 8);

    float m_r[4], l_r[4];
    floatx4 oacc[4] = {};
#pragma unroll
    for (int r = 0; r < 4; r++) { m_r[r] = -1e30f; l_r[r] = 0.0f; }

    for (int kt = 0; kt < S_LEN / 64; kt++) {
        int k0 = kt * 64;
        __syncthreads();   // all waves done reading Vt of previous tile
        {
            int key = tid & 63, dseg = tid >> 6;
            const unsigned short* vp = vb + (size_t)(k0 + key) * DK + dseg * 16;
            ushort8v v0 = *(const ushort8v*)vp;
            ushort8v v1 = *(const ushort8v*)(vp + 8);
#pragma unroll
            for (int j = 0; j < 8; j++) {
                Vt[(dseg * 16 + j) * 64 + key] = v0[j];
                Vt[(dseg * 16 + 8 + j) * 64 + key] = v1[j];
            }
        }
        // scores: 16x64 per wave
        floatx4 sf[4];
#pragma unroll
        for (int ni = 0; ni < 4; ni++) {
            floatx4 z = {};
#pragma unroll
            for (int ks = 0; ks < 2; ks++) {
                bf16x8 bk = *(const bf16x8*)(kfb + (size_t)(k0 + ni * 16 + l16) * DK + ks * 32 + quad * 8);
                z = __builtin_amdgcn_mfma_f32_16x16x32_bf16(aq[ks], bk, z, 0, 0, 0);
            }
            sf[ni] = z;
        }
        // scale + mask
#pragma unroll
        for (int ni = 0; ni < 4; ni++) {
            int key = k0 + ni * 16 + l16;
            int wi = key >> 5, bit = key & 31;
#pragma unroll
            for (int r = 0; r < 4; r++) {
                int qrow = q0 + quad * 4 + r;
                unsigned wmask = mb[qrow * 64 + wi];
                float s = sf[ni][r] * scale;
                sf[ni][r] = ((wmask >> bit) & 1u) ? s : -1e9f;
            }
        }
        // online softmax
        float mloc[4];
#pragma unroll
        for (int r = 0; r < 4; r++)
            mloc[r] = fmaxf(fmaxf(sf[0][r], sf[1][r]), fmaxf(sf[2][r], sf[3][r]));
#pragma unroll
        for (int off = 1; off < 16; off <<= 1)
#pragma unroll
            for (int r = 0; r < 4; r++) mloc[r] = fmaxf(mloc[r], __shfl_xor(mloc[r], off));
        float alpha[4];
#pragma unroll
        for (int r = 0; r < 4; r++) {
            float mn = fmaxf(m_r[r], mloc[r]);
            alpha[r] = __expf(m_r[r] - mn);
            m_r[r] = mn;
        }
        float rs[4] = {0.f, 0.f, 0.f, 0.f};
#pragma unroll
        for (int ni = 0; ni < 4; ni++)
#pragma unroll
            for (int r = 0; r < 4; r++) {
                float p = __expf(sf[ni][r] - m_r[r]);
                sf[ni][r] = p;
                rs[r] += p;
            }
#pragma unroll
        for (int off = 1; off < 16; off <<= 1)
#pragma unroll
            for (int r = 0; r < 4; r++) rs[r] += __shfl_xor(rs[r], off);
#pragma unroll
        for (int r = 0; r < 4; r++) l_r[r] = l_r[r] * alpha[r] + rs[r];
#pragma unroll
        for (int ni = 0; ni < 4; ni++)
#pragma unroll
            for (int r = 0; r < 4; r++) oacc[ni][r] *= alpha[r];
        // P -> LDS (C-layout -> A-layout round trip)
#pragma unroll
        for (int ni = 0; ni < 4; ni++)
#pragma unroll
            for (int r = 0; r < 4; r++)
                Plds[wid][(quad * 4 + r) * 64 + ni * 16 + l16] = f2bf(sf[ni][r]);
        __syncthreads();   // Vt staged + P visible
        bf16x8 pa[2];
#pragma unroll
        for (int ks = 0; ks < 2; ks++)
            pa[ks] = *(const bf16x8*)&Plds[wid][l16 * 64 + ks * 32 + quad * 8];
#pragma unroll
        for (int ni = 0; ni < 4; ni++) {
#pragma unroll
            for (int ks = 0; ks < 2; ks++) {
                bf16x8 bv = *(const bf16x8*)&Vt[(ni * 16 + l16) * 64 + ks * 32 + quad * 8];
                oacc[ni] = __builtin_amdgcn_mfma_f32_16x16x32_bf16(pa[ks], bv, oacc[ni], 0, 0, 0);
            }
        }
    }
    // epilogue: normalize, write merged-head ctx (bf16 [B*S][DM])
    float inv[4];
#pragma unroll
    for (int r = 0; r < 4; r++) inv[r] = 1.0f / l_r[r];
#pragma unroll
    for (int ni = 0; ni < 4; ni++) {
        int d = ni * 16 + l16;
#pragma unroll
        for (int r = 0; r < 4; r++) {
            int s = q0 + quad * 4 + r;
            float val = oacc[ni][r] * inv[r];
            ctx[(size_t)(b * S_LEN + s) * DM + h * DK + d] = f2bf(val);
        }
    }
}

// ---------------- RMSNorm ----------------
__global__ __launch_bounds__(256) void k_rmsnorm(const float* __restrict__ x,
                                                 const float* __restrict__ gamma,
                                                 float* __restrict__ out) {
    int row = blockIdx.x, tid = threadIdx.x;
    const floatx4* xr = (const floatx4*)(x + (size_t)row * DM);
    floatx4 v = xr[tid];
    float ss = v[0] * v[0] + v[1] * v[1] + v[2] * v[2] + v[3] * v[3];
#pragma unroll
    for (int off = 1; off < 64; off <<= 1) ss += __shfl_xor(ss, off);
    __shared__ float red[4];
    int lane = tid & 63, wid = tid >> 6;
    if (lane == 0) red[wid] = ss;
    __syncthreads();
    float tot = red[0] + red[1] + red[2] + red[3];
    float rms = rsqrtf(tot * (1.0f / DM) + 1e-6f);
    floatx4 g = ((const floatx4*)gamma)[tid];
    floatx4 o;
    o[0] = v[0] * rms * g[0];
    o[1] = v[1] * rms * g[1];
    o[2] = v[2] * rms * g[2];
    o[3] = v[3] * rms * g[3];
    ((floatx4*)(out + (size_t)row * DM))[tid] = o;
}

extern "C" void kernel_launch(void* const* d_in, const int* in_sizes, int n_in,
                              void* d_out, int out_size, void* d_ws, size_t ws_size,
                              hipStream_t stream) {
    const float* Q = (const float*)d_in[0];
    const float* K = (const float*)d_in[1];
    const float* V = (const float*)d_in[2];
    const int* mask = (const int*)d_in[3];
    const float* wq = (const float*)d_in[4];
    const float* bq = (const float*)d_in[5];
    const float* wk = (const float*)d_in[6];
    const float* bk = (const float*)d_in[7];
    const float* wv = (const float*)d_in[8];
    const float* bv = (const float*)d_in[9];
    const float* wo = (const float*)d_in[10];
    const float* bo = (const float*)d_in[11];
    const float* wnq = (const float*)d_in[12];
    const float* bnq = (const float*)d_in[13];
    const float* wnk = (const float*)d_in[14];
    const float* bnk = (const float*)d_in[15];
    const float* temp = (const float*)d_in[16];
    const float* gamma = (const float*)d_in[17];

    char* w = (char*)d_ws;
    size_t o = 0;
    auto alloc = [&](size_t bytes) {
        char* p = w + o;
        o += (bytes + 255) & ~(size_t)255;
        return p;
    };
    unsigned short* Qb = (unsigned short*)alloc((size_t)BS * DM * 2);
    unsigned short* Kb = (unsigned short*)alloc((size_t)BS * DM * 2);
    unsigned short* Vb = (unsigned short*)alloc((size_t)BS * DM * 2);
    unsigned short* Wqt = (unsigned short*)alloc((size_t)DM * DM * 2);
    unsigned short* Wkt = (unsigned short*)alloc((size_t)DM * DM * 2);
    unsigned short* Wvt = (unsigned short*)alloc((size_t)DM * DM * 2);
    unsigned short* Wot = (unsigned short*)alloc((size_t)DM * DM * 2);
    unsigned short* wnqt = (unsigned short*)alloc((size_t)DK * DK * 2);
    unsigned short* wnkt = (unsigned short*)alloc((size_t)DK * DK * 2);
    unsigned short* qh = (unsigned short*)alloc((size_t)BHS * DK * 2);
    unsigned short* kh = (unsigned short*)alloc((size_t)BHS * DK * 2);
    unsigned short* vh = (unsigned short*)alloc((size_t)BHS * DK * 2);
    unsigned short* qfb = (unsigned short*)alloc((size_t)BHS * DK * 2);
    unsigned short* kfb = (unsigned short*)alloc((size_t)BHS * DK * 2);
    unsigned int* mb = (unsigned int*)alloc((size_t)S_LEN * (S_LEN / 32) * 4);
    unsigned short* ctx = (unsigned short*)alloc((size_t)BS * DM * 2);
    float* outt = (float*)alloc((size_t)BS * DM * 4);

    k_convert<<<dim3(3 * BS * DM / 4 / 256), 256, 0, stream>>>(Q, K, V, Qb, Kb, Vb);
    k_transpose<<<dim3(32, 32, 4), 256, 0, stream>>>(wq, wk, wv, wo, Wqt, Wkt, Wvt, Wot, DM);
    k_transpose<<<dim3(2, 2, 2), 256, 0, stream>>>(wnq, wnk, wnq, wnq, wnqt, wnkt, wnqt, wnqt, DK);
    k_maskpack<<<dim3(S_LEN * 64 / 256), 256, 0, stream>>>(mask, mb);

    k_gemm128<<<dim3(8, 32), 256, 0, stream>>>(Qb, Wqt, bq, qh, nullptr, 0);
    k_gemm128<<<dim3(8, 32), 256, 0, stream>>>(Kb, Wkt, bk, kh, nullptr, 0);
    k_gemm128<<<dim3(8, 32), 256, 0, stream>>>(Vb, Wvt, bv, vh, nullptr, 0);

    k_feature<<<dim3(BHS / 64), 256, 0, stream>>>(qh, wnqt, bnq, qfb);
    k_feature<<<dim3(BHS / 64), 256, 0, stream>>>(kh, wnkt, bnk, kfb);

    k_attn<<<dim3(S_LEN / 64, BATCH * NH), 256, 0, stream>>>(qfb, kfb, vh, mb, temp, ctx);

    k_gemm128<<<dim3(8, 32), 256, 0, stream>>>(ctx, Wot, bo, nullptr, outt, 1);
    k_rmsnorm<<<dim3(BS), 256, 0, stream>>>(outt, gamma, (float*)d_out);
}